// Round 1
// 196.841 us; speedup vs baseline: 1.0285x; 1.0285x over previous
//
#include <hip/hip_runtime.h>
#include <math.h>

#define B_ 32
#define D_ 16
#define H_ 256
#define W_ 256
#define N_ 512
#define TS 64          // tile size
#define NT 8           // tiles per dim (N_/TS)
#define NPAIR 36       // NT*(NT+1)/2 triangle tile-pairs
#define RS 20          // padded LDS row stride in floats (80B, 16B-aligned, conflict-free)

// Phase 1: gather embeddings at keypoint locations ONCE into a compact
// [B, N, D] buffer in the workspace, and precompute sq = mean_d(e^2).
// One thread per (b, n, d): 32*512*16 = 262144 threads = 1024 blocks.
// This removes the 9x-redundant, fully-uncoalesced gather the pair-tile
// kernel used to do per tile-pair (2.36M line transactions -> 262K).
__global__ __launch_bounds__(256) void gather_k(const float* __restrict__ pred,
                                                const float* __restrict__ kpt,
                                                float* __restrict__ emb,
                                                float* __restrict__ sq) {
    int gid = blockIdx.x * 256 + threadIdx.x;   // 0 .. B*N*D-1
    int d   = gid & (D_ - 1);
    int pt  = gid >> 4;                          // b*N + n
    int b   = pt >> 9;                           // N = 512

    float k0 = kpt[pt * 2 + 0];
    float k1 = kpt[pt * 2 + 1];
    int y = (int)floorf(k0 * (float)W_);
    int x = (int)floorf(k1 * (float)H_);
    y = min(max(y, 0), H_ - 1);
    x = min(max(x, 0), W_ - 1);

    float v = pred[(((size_t)b * D_ + d) * H_ + y) * W_ + x];
    emb[(size_t)pt * D_ + d] = v;                // coalesced 64B per 16 lanes

    // 16-lane butterfly to get sum_d v^2 for this point
    float s = v * v;
    s += __shfl_xor(s, 1);
    s += __shfl_xor(s, 2);
    s += __shfl_xor(s, 4);
    s += __shfl_xor(s, 8);
    if (d == 0) sq[pt] = s * (1.0f / (float)D_);
}

// Phase 2: one block per (batch, triangle tile-pair).
// grid = 32 * 36 = 1152 blocks, 256 threads.
// Stages its two 64-row slices from the COMPACT buffer (coalesced float4,
// L2-resident 4MB) instead of re-gathering from pred.
__global__ __launch_bounds__(256) void tagloss_k(const float* __restrict__ emb,
                                                 const float* __restrict__ sqg,
                                                 const int* __restrict__ vis,
                                                 const int* __restrict__ tag,
                                                 float* __restrict__ out) {
    __shared__ float eA[TS * RS];   // 5120 B
    __shared__ float eB[TS * RS];   // 5120 B
    __shared__ float sqA[TS], sqB[TS];   // mean(row^2)
    __shared__ int   tgA[TS], tgB[TS];
    __shared__ float msA[TS], msB[TS];
    __shared__ float redA[4], redK[4];

    int bi = blockIdx.x;
    int b  = bi / NPAIR;
    int p  = bi - b * NPAIR;
    // triangle decode: p -> (ti, tj), ti <= tj
    int ti = 0, rem = p;
    while (rem >= (NT - ti)) { rem -= (NT - ti); ++ti; }
    int tj = ti + rem;

    int t = threadIdx.x;

    // ---- staging: 128 rows (64 A + 64 B), 2 threads per row, 8 channels each
    {
        int r    = t >> 1;        // 0..127
        int half = t & 1;         // which 8 channels
        int inA  = (r < TS);
        int rr   = inA ? r : (r - TS);
        int n    = (inA ? ti : tj) * TS + rr;
        const float4* src = (const float4*)&emb[((size_t)(b * N_ + n)) * D_ + half * 8];
        float4 v0 = src[0];
        float4 v1 = src[1];
        float* dst = (inA ? eA : eB) + rr * RS + half * 8;
        ((float4*)dst)[0] = v0;
        ((float4*)dst)[1] = v1;
        if (half == 0) {
            float sqm = sqg[b * N_ + n];
            int   tgv = tag[b * N_ + n];
            float msv = (vis[b * N_ + n] > 0) ? 1.0f : 0.0f;
            if (inA) { sqA[rr] = sqm; tgA[rr] = tgv; msA[rr] = msv; }
            else     { sqB[rr] = sqm; tgB[rr] = tgv; msB[rr] = msv; }
        }
    }
    // per-thread piece of K = sum over full batch mask (redundant across blocks)
    float kpart = ((vis[b * N_ + t] > 0) ? 1.0f : 0.0f) +
                  ((vis[b * N_ + t + 256] > 0) ? 1.0f : 0.0f);
    __syncthreads();

    // ---- pair tile: thread owns row r2 of A-tile, quarter q of m-range
    int r2 = t >> 2;
    int q  = t & 3;
    const float4* ap = (const float4*)&eA[r2 * RS];
    float4 a0 = ap[0], a1 = ap[1], a2 = ap[2], a3 = ap[3];
    float sa = sqA[r2];
    int   tn = tgA[r2];
    float mn = msA[r2];

    float acc = 0.0f;
#pragma unroll 4
    for (int i = 0; i < 16; ++i) {
        int m = (i << 2) | q;
        const float4* bp = (const float4*)&eB[m * RS];
        float4 b0 = bp[0], b1 = bp[1], b2 = bp[2], b3 = bp[3];
        float dot;
        dot  = a0.x * b0.x; dot += a0.y * b0.y; dot += a0.z * b0.z; dot += a0.w * b0.w;
        dot += a1.x * b1.x; dot += a1.y * b1.y; dot += a1.z * b1.z; dot += a1.w * b1.w;
        dot += a2.x * b2.x; dot += a2.y * b2.y; dot += a2.z * b2.z; dot += a2.w * b2.w;
        dot += a3.x * b3.x; dot += a3.y * b3.y; dot += a3.z * b3.z; dot += a3.w * b3.w;
        float ex = sa + sqB[m] - 0.125f * dot;     // mean((a-b)^2)
        float ps = 2.0f / (1.0f + __expf(ex));     // pred_sim (always > 0 when finite)
        float ts = (tn == tgB[m]) ? 1.0f : 0.0f;   // true_sim
        float di = ps - ts;
        acc += di * di * msB[m];                   // wgt==10 hoisted to epilogue
    }
    acc *= mn;

    // ---- block reduction (wave64 shuffles, then 4 waves via LDS)
#pragma unroll
    for (int off = 32; off; off >>= 1) {
        acc   += __shfl_down(acc, off);
        kpart += __shfl_down(kpart, off);
    }
    if ((t & 63) == 0) { redA[t >> 6] = acc; redK[t >> 6] = kpart; }
    __syncthreads();
    if (t == 0) {
        float tot = redA[0] + redA[1] + redA[2] + redA[3];
        float K   = redK[0] + redK[1] + redK[2] + redK[3];
        float tilew = (ti == tj) ? 1.0f : 2.0f;    // triangle symmetry
        float scale = 10.0f * tilew / (fmaxf(K * K, 1.0f) * (float)B_);
        atomicAdd(out, tot * scale);
    }
}

extern "C" void kernel_launch(void* const* d_in, const int* in_sizes, int n_in,
                              void* d_out, int out_size, void* d_ws, size_t ws_size,
                              hipStream_t stream) {
    const float* pred = (const float*)d_in[0];
    const float* kpt  = (const float*)d_in[1];
    const int*   vis  = (const int*)d_in[2];
    const int*   tag  = (const int*)d_in[3];
    float* out = (float*)d_out;

    float* emb = (float*)d_ws;                    // B*N*D floats = 4 MiB
    float* sq  = emb + (size_t)B_ * N_ * D_;      // B*N floats = 64 KiB

    hipMemsetAsync(out, 0, sizeof(float) * out_size, stream);
    gather_k<<<(B_ * N_ * D_) / 256, 256, 0, stream>>>(pred, kpt, emb, sq);
    tagloss_k<<<B_ * NPAIR, 256, 0, stream>>>(emb, sq, vis, tag, out);
}

// Round 3
// 194.494 us; speedup vs baseline: 1.0409x; 1.0121x over previous
//
#include <hip/hip_runtime.h>
#include <math.h>

#define B_ 32
#define D_ 16
#define H_ 256
#define W_ 256
#define N_ 512
#define TS 64          // tile size
#define NT 8           // tiles per dim (N_/TS)
#define NPAIR 36       // NT*(NT+1)/2 triangle tile-pairs
#define RS 20          // padded LDS row stride in floats (80B, 16B-aligned, conflict-free)

// Phase 1: gather embeddings at keypoint locations ONCE into a compact
// [B, N, D] buffer in the workspace, and precompute sq = mean_d(e^2).
// One thread per (b, n, d): 32*512*16 = 262144 threads = 1024 blocks.
// Block 0 also zeroes the output accumulator -- out is only consumed by
// tagloss_k's atomicAdd, which is stream-ordered after this kernel, so the
// separate hipMemsetAsync dispatch is folded away (3 dispatches -> 2).
// NOTE: cooperative-launch fusion of the two kernels was tried and FAILED
// under the harness's graph-capture path (R2) -- keep stream-ordered dispatches.
__global__ __launch_bounds__(256) void gather_k(const float* __restrict__ pred,
                                                const float* __restrict__ kpt,
                                                float* __restrict__ emb,
                                                float* __restrict__ sq,
                                                float* __restrict__ out,
                                                int out_n) {
    if (blockIdx.x == 0) {
        for (int i = threadIdx.x; i < out_n; i += 256) out[i] = 0.0f;
    }

    int gid = blockIdx.x * 256 + threadIdx.x;   // 0 .. B*N*D-1
    int d   = gid & (D_ - 1);
    int pt  = gid >> 4;                          // b*N + n
    int b   = pt >> 9;                           // N = 512

    float k0 = kpt[pt * 2 + 0];
    float k1 = kpt[pt * 2 + 1];
    int y = (int)floorf(k0 * (float)W_);
    int x = (int)floorf(k1 * (float)H_);
    y = min(max(y, 0), H_ - 1);
    x = min(max(x, 0), W_ - 1);

    float v = pred[(((size_t)b * D_ + d) * H_ + y) * W_ + x];
    emb[(size_t)pt * D_ + d] = v;                // coalesced 64B per 16 lanes

    // 16-lane butterfly to get sum_d v^2 for this point
    float s = v * v;
    s += __shfl_xor(s, 1);
    s += __shfl_xor(s, 2);
    s += __shfl_xor(s, 4);
    s += __shfl_xor(s, 8);
    if (d == 0) sq[pt] = s * (1.0f / (float)D_);
}

// Phase 2: one block per (batch, triangle tile-pair).
// grid = 32 * 36 = 1152 blocks, 256 threads.
// Stages its two 64-row slices from the COMPACT buffer (coalesced float4,
// L2-resident 4MB) instead of re-gathering from pred.
__global__ __launch_bounds__(256) void tagloss_k(const float* __restrict__ emb,
                                                 const float* __restrict__ sqg,
                                                 const int* __restrict__ vis,
                                                 const int* __restrict__ tag,
                                                 float* __restrict__ out) {
    __shared__ float eA[TS * RS];   // 5120 B
    __shared__ float eB[TS * RS];   // 5120 B
    __shared__ float sqA[TS], sqB[TS];   // mean(row^2)
    __shared__ int   tgA[TS], tgB[TS];
    __shared__ float msA[TS], msB[TS];
    __shared__ float redA[4], redK[4];

    int bi = blockIdx.x;
    int b  = bi / NPAIR;
    int p  = bi - b * NPAIR;
    // triangle decode: p -> (ti, tj), ti <= tj
    int ti = 0, rem = p;
    while (rem >= (NT - ti)) { rem -= (NT - ti); ++ti; }
    int tj = ti + rem;

    int t = threadIdx.x;

    // ---- staging: 128 rows (64 A + 64 B), 2 threads per row, 8 channels each
    {
        int r    = t >> 1;
        int half = t & 1;
        int inA  = (r < TS);
        int rr   = inA ? r : (r - TS);
        int n    = (inA ? ti : tj) * TS + rr;
        const float4* src = (const float4*)&emb[((size_t)(b * N_ + n)) * D_ + half * 8];
        float4 v0 = src[0];
        float4 v1 = src[1];
        float* dst = (inA ? eA : eB) + rr * RS + half * 8;
        ((float4*)dst)[0] = v0;
        ((float4*)dst)[1] = v1;
        if (half == 0) {
            float sqm = sqg[b * N_ + n];
            int   tgv = tag[b * N_ + n];
            float msv = (vis[b * N_ + n] > 0) ? 1.0f : 0.0f;
            if (inA) { sqA[rr] = sqm; tgA[rr] = tgv; msA[rr] = msv; }
            else     { sqB[rr] = sqm; tgB[rr] = tgv; msB[rr] = msv; }
        }
    }
    // per-thread piece of K = sum over full batch mask (redundant across blocks)
    float kpart = ((vis[b * N_ + t] > 0) ? 1.0f : 0.0f) +
                  ((vis[b * N_ + t + 256] > 0) ? 1.0f : 0.0f);
    __syncthreads();

    // ---- pair tile: thread owns row r2 of A-tile, quarter q of m-range
    int r2 = t >> 2;
    int q  = t & 3;
    const float4* ap = (const float4*)&eA[r2 * RS];
    float4 a0 = ap[0], a1 = ap[1], a2 = ap[2], a3 = ap[3];
    float sa = sqA[r2];
    int   tn = tgA[r2];
    float mn = msA[r2];

    float acc = 0.0f;
#pragma unroll 4
    for (int i = 0; i < 16; ++i) {
        int m = (i << 2) | q;
        const float4* bp = (const float4*)&eB[m * RS];
        float4 b0 = bp[0], b1 = bp[1], b2 = bp[2], b3 = bp[3];
        float dot;
        dot  = a0.x * b0.x; dot += a0.y * b0.y; dot += a0.z * b0.z; dot += a0.w * b0.w;
        dot += a1.x * b1.x; dot += a1.y * b1.y; dot += a1.z * b1.z; dot += a1.w * b1.w;
        dot += a2.x * b2.x; dot += a2.y * b2.y; dot += a2.z * b2.z; dot += a2.w * b2.w;
        dot += a3.x * b3.x; dot += a3.y * b3.y; dot += a3.z * b3.z; dot += a3.w * b3.w;
        float ex = sa + sqB[m] - 0.125f * dot;     // mean((a-b)^2)
        float ps = 2.0f / (1.0f + __expf(ex));     // pred_sim (always > 0 when finite)
        float ts = (tn == tgB[m]) ? 1.0f : 0.0f;   // true_sim
        float di = ps - ts;
        acc += di * di * msB[m];                   // wgt==10 hoisted to epilogue
    }
    acc *= mn;

    // ---- block reduction (wave64 shuffles, then 4 waves via LDS)
#pragma unroll
    for (int off = 32; off; off >>= 1) {
        acc   += __shfl_down(acc, off);
        kpart += __shfl_down(kpart, off);
    }
    if ((t & 63) == 0) { redA[t >> 6] = acc; redK[t >> 6] = kpart; }
    __syncthreads();
    if (t == 0) {
        float tot = redA[0] + redA[1] + redA[2] + redA[3];
        float K   = redK[0] + redK[1] + redK[2] + redK[3];
        float tilew = (ti == tj) ? 1.0f : 2.0f;    // triangle symmetry
        float scale = 10.0f * tilew / (fmaxf(K * K, 1.0f) * (float)B_);
        atomicAdd(out, tot * scale);
    }
}

extern "C" void kernel_launch(void* const* d_in, const int* in_sizes, int n_in,
                              void* d_out, int out_size, void* d_ws, size_t ws_size,
                              hipStream_t stream) {
    const float* pred = (const float*)d_in[0];
    const float* kpt  = (const float*)d_in[1];
    const int*   vis  = (const int*)d_in[2];
    const int*   tag  = (const int*)d_in[3];
    float* out = (float*)d_out;

    float* emb = (float*)d_ws;                    // B*N*D floats = 4 MiB
    float* sq  = emb + (size_t)B_ * N_ * D_;      // B*N floats = 64 KiB

    gather_k<<<(B_ * N_ * D_) / 256, 256, 0, stream>>>(pred, kpt, emb, sq, out, out_size);
    tagloss_k<<<B_ * NPAIR, 256, 0, stream>>>(emb, sq, vis, tag, out);
}